// Round 10
// baseline (47.578 us; speedup 1.0000x reference)
//
#include <hip/hip_runtime.h>

#define BB 4
#define NN 8192
#define THREADS 256
#define COLS_PER_BLK 2048            // NN / 4 col-quarters
#define CC 512                       // cols staged in LDS per chunk
#define NCHUNK (COLS_PER_BLK / CC)   // 4
#define ROWS_PER_BLK 128             // 4 waves x 32 rows

typedef float f32x16 __attribute__((ext_vector_type(16)));
typedef __bf16 bf16x8 __attribute__((ext_vector_type(8)));

// ws layout (bytes):
//   [0, 256K)          : min1[32768], min2[32768] (uint bit patterns of d^2)
//   [256K, 256K+1M)    : A-vecs (gt role):   (b*8192+n)*32B, two uint4 halves
//   [256K+1M, 256K+2M) : B-vecs (pred role): same
#define AVEC_OFF (1u << 18)
#define BVEC_OFF ((1u << 18) + (1u << 20))

__device__ inline float max3f(float a, float b, float c) {
    float d;
    asm("v_max3_f32 %0, %1, %2, %3" : "=v"(d) : "v"(a), "v"(b), "v"(c));
    return d;
}

__device__ inline unsigned short brne(float x) {   // fp32 -> bf16 RNE bits
    unsigned u = __float_as_uint(x);
    return (unsigned short)((u + 0x7FFFu + ((u >> 16) & 1)) >> 16);
}
__device__ inline unsigned pk(unsigned a, unsigned b) { return a | (b << 16); }

// Build slot vectors + init mins. 65536 threads: tid = role(2) x batch(4) x n(8192)
__global__ __launch_bounds__(256) void cd_pre_kernel(
    const float* __restrict__ pred, const float* __restrict__ gt,
    const float* __restrict__ coords, unsigned int* __restrict__ ws)
{
    int tid = blockIdx.x * 256 + threadIdx.x;
    ws[tid] = 0x7F800000u;            // mins[65536] = +inf

    int role = tid >> 15;             // 0: gt -> A-vec, 1: pred -> B-vec
    int rem  = tid & 32767;
    int b    = rem >> 13;
    int n    = rem & 8191;
    const float* sb = (role ? pred : gt) + b * 3 * NN;
    const float* cb = coords + b * 3 * NN;
    float x = cb[0 * NN + n] + sb[0 * NN + n];
    float y = cb[1 * NN + n] + sb[1 * NN + n];
    float z = cb[2 * NN + n] + sb[2 * NN + n];
    float w = -0.5f * fmaf(x, x, fmaf(y, y, z * z));

    unsigned short hx = brne(x); unsigned short lx = brne(x - __uint_as_float((unsigned)hx << 16));
    unsigned short hy = brne(y); unsigned short ly = brne(y - __uint_as_float((unsigned)hy << 16));
    unsigned short hz = brne(z); unsigned short lz = brne(z - __uint_as_float((unsigned)hz << 16));
    unsigned short hw = brne(w); unsigned short lw = brne(w - __uint_as_float((unsigned)hw << 16));
    const unsigned short ONE = 0x3F80;

    uint4 h0, h1;
    if (role == 0) {   // A slots: hx hy hz lx ly lz hx hy | hz hw lw 1 1 0 0 0
        h0 = make_uint4(pk(hx, hy), pk(hz, lx), pk(ly, lz), pk(hx, hy));
        h1 = make_uint4(pk(hz, hw), pk(lw, ONE), pk(ONE, 0), 0u);
    } else {           // B slots: hx hy hz hx hy hz lx ly | lz 1 1 hw lw 0 0 0
        h0 = make_uint4(pk(hx, hy), pk(hz, hx), pk(hy, hz), pk(lx, ly));
        h1 = make_uint4(pk(lz, ONE), pk(ONE, hw), pk(lw, 0), 0u);
    }
    // halves swapped for odd n (bank swizzle; reader XORs hi with n&1)
    uint4* out = (uint4*)((char*)ws + (role ? BVEC_OFF : AVEC_OFF)) + (unsigned)(b * 8192 + n) * 2;
    int sw = n & 1;
    out[sw]     = h0;
    out[sw ^ 1] = h1;
}

// grid 1024: (cq 4) x (row panel 64) x (batch 4); block = 4 waves x 32 rows, scans 2048 cols
__global__ __launch_bounds__(256) void cd_mfma_kernel(unsigned int* ws)
{
    __shared__ uint4 colv[CC * 2];                 // 16 KB staged B-vecs
    __shared__ unsigned int colm[COLS_PER_BLK];    // 8 KB col-max u bits
    __shared__ unsigned int rowm[ROWS_PER_BLK];    // row-max u bits

    int bid = blockIdx.x;
    int cq = bid & 3;
    int pb = (bid >> 2) & 63;
    int b  = bid >> 8;

    int tid  = threadIdx.x;
    int w    = tid >> 6;
    int lane = tid & 63;
    int cl   = lane & 31;
    int hi   = lane >> 5;

#pragma unroll
    for (int i = 0; i < COLS_PER_BLK / THREADS; i++) colm[tid + i * THREADS] = 0xFF800000u;
    if (tid < ROWS_PER_BLK) rowm[tid] = 0xFF800000u;

    // A fragment: this lane's row point, half (hi ^ parity)
    const uint4* avec = (const uint4*)((const char*)ws + AVEC_OFF);
    int arow = b * 8192 + pb * 128 + w * 32 + cl;
    uint4 araw = avec[(unsigned)arow * 2 + (hi ^ (cl & 1))];
    bf16x8 afrag = __builtin_bit_cast(bf16x8, araw);

    const uint4* bvec = (const uint4*)((const char*)ws + BVEC_OFF);
    f32x16 zacc{};                                  // zero accumulator

    float rm[16];
#pragma unroll
    for (int j = 0; j < 16; j++) rm[j] = -3.0e38f;

    int lanebase = cl * 2 + (hi ^ (cl & 1));

    for (int ck = 0; ck < NCHUNK; ++ck) {
        __syncthreads();                            // prior chunk consumed
        const uint4* src = bvec + (unsigned)(b * 8192 + cq * COLS_PER_BLK + ck * CC) * 2;
#pragma unroll
        for (int i = 0; i < (CC * 2) / THREADS; i++)
            colv[tid + i * THREADS] = src[tid + i * THREADS];
        __syncthreads();

        unsigned cmbase = (unsigned)(ck * CC + cl);
#pragma unroll
        for (int t = 0; t < CC / 32; t++) {
            bf16x8 bf = __builtin_bit_cast(bf16x8, colv[t * 64 + lanebase]);
            f32x16 d = __builtin_amdgcn_mfma_f32_32x32x16_bf16(afrag, bf, zacc, 0, 0, 0);
            // row-max fold (rows of this lane's hi live in regs per C-layout)
#pragma unroll
            for (int j = 0; j < 16; j++) rm[j] = fmaxf(rm[j], d[j]);
            // col fold: 16 rows -> 1, then LDS min on bits (float-max for u<=~0)
            float q0 = max3f(d[0], d[1], d[2]);
            float q1 = max3f(d[3], d[4], d[5]);
            float q2 = max3f(d[6], d[7], d[8]);
            float q3 = max3f(d[9], d[10], d[11]);
            float q4 = max3f(d[12], d[13], d[14]);
            float v0 = max3f(q0, q1, d[15]);
            float v1 = max3f(q2, q3, q4);
            float cf = fmaxf(v0, v1);
            atomicMin(&colm[cmbase + t * 32], __float_as_uint(cf));
        }
    }

    // flush per-lane row maxima into block rowm (C-layout row formula, m101-verified)
#pragma unroll
    for (int j = 0; j < 16; j++) {
        int rl = w * 32 + (j & 3) + 8 * (j >> 2) + 4 * hi;
        atomicMin(&rowm[rl], __float_as_uint(rm[j]));
    }
    __syncthreads();

    unsigned int* min1 = ws;
    unsigned int* min2 = ws + BB * NN;
    if (tid < ROWS_PER_BLK) {
        float u = __uint_as_float(rowm[tid]);
        float d2 = fmaxf(-2.0f * u, 0.0f);
        atomicMin(&min1[b * NN + pb * 128 + tid], __float_as_uint(d2));
    }
#pragma unroll
    for (int i = 0; i < COLS_PER_BLK / THREADS; i++) {
        int c = tid + i * THREADS;
        float u = __uint_as_float(colm[c]);
        float d2 = fmaxf(-2.0f * u, 0.0f);
        atomicMin(&min2[b * NN + cq * COLS_PER_BLK + c], __float_as_uint(d2));
    }
}

__global__ __launch_bounds__(1024) void cd_reduce_kernel(const unsigned int* __restrict__ mins,
                                                         float* __restrict__ out)
{
    float s = 0.0f;
    for (int k = 0; k < 2 * BB * NN / 1024; ++k)
        s += __uint_as_float(mins[threadIdx.x + k * 1024]);
#pragma unroll
    for (int off = 32; off > 0; off >>= 1)
        s += __shfl_down(s, off, 64);
    __shared__ float wsum[16];
    int wave = threadIdx.x >> 6;
    if ((threadIdx.x & 63) == 0) wsum[wave] = s;
    __syncthreads();
    if (threadIdx.x == 0) {
        float t = 0.0f;
#pragma unroll
        for (int v = 0; v < 16; ++v) t += wsum[v];
        out[0] = t / (float)BB;
    }
}

extern "C" void kernel_launch(void* const* d_in, const int* in_sizes, int n_in,
                              void* d_out, int out_size, void* d_ws, size_t ws_size,
                              hipStream_t stream) {
    const float* pred   = (const float*)d_in[0];
    const float* gt     = (const float*)d_in[1];
    const float* coords = (const float*)d_in[2];
    float* out = (float*)d_out;
    unsigned int* ws = (unsigned int*)d_ws;

    hipLaunchKernelGGL(cd_pre_kernel, dim3(256), dim3(256), 0, stream,
                       pred, gt, coords, ws);
    hipLaunchKernelGGL(cd_mfma_kernel, dim3(1024), dim3(256), 0, stream, ws);
    hipLaunchKernelGGL(cd_reduce_kernel, dim3(1), dim3(1024), 0, stream, ws, out);
}